// Round 14
// baseline (410.768 us; speedup 1.0000x reference)
//
#include <hip/hip_runtime.h>
#include <hip/hip_bf16.h>

#define BB 8
#define DD 64
#define NNODE 1024
#define LLL 12
#define EE 128
#define NEGV -9.0e15f

typedef _Float16 f16;
typedef _Float16 f16x2 __attribute__((ext_vector_type(2)));
typedef _Float16 f16x4 __attribute__((ext_vector_type(4)));
typedef _Float16 f16x8 __attribute__((ext_vector_type(8)));
typedef float f32x4 __attribute__((ext_vector_type(4)));

// ================= 128^2 GEMM core helpers ==================================

__device__ __forceinline__ void stage_tile(const char* g, int ld, char* lds, int t) {
    int wid = t >> 6, lane = t & 63;
#pragma unroll
    for (int it = 0; it < 4; it++) {
        int cbase = it * 256 + wid * 64;
        int c = cbase + lane;
        int row = c >> 3, p = c & 7;
        int gch = p ^ (row & 7);
        const char* src = g + (size_t)row * ld + gch * 16;
        char* dst = lds + (size_t)cbase * 16;
        __builtin_amdgcn_global_load_lds(
            (const __attribute__((address_space(1))) unsigned int*)src,
            (__attribute__((address_space(3))) unsigned int*)dst, 16, 0, 0);
    }
}

__device__ __forceinline__ void mma_tile(const char* As, const char* Bs, int t,
                                         f32x4 acc[4][4]) {
    int lane = t & 63, wid = t >> 6;
    int wr = (wid >> 1) * 64, wc = (wid & 1) * 64;
    int lrow = lane & 15, lk = lane >> 4;
#pragma unroll
    for (int kk = 0; kk < 2; kk++) {
        f16x8 af[4], bf[4];
#pragma unroll
        for (int m = 0; m < 4; m++) {
            int row = wr + m * 16 + lrow;
            int p = (kk * 4 + lk) ^ (row & 7);
            af[m] = *(const f16x8*)(As + row * 128 + p * 16);
        }
#pragma unroll
        for (int n = 0; n < 4; n++) {
            int row = wc + n * 16 + lrow;
            int p = (kk * 4 + lk) ^ (row & 7);
            bf[n] = *(const f16x8*)(Bs + row * 128 + p * 16);
        }
#pragma unroll
        for (int m = 0; m < 4; m++)
#pragma unroll
            for (int n = 0; n < 4; n++)
                acc[m][n] = __builtin_amdgcn_mfma_f32_16x16x32_f16(
                    af[m], bf[n], acc[m][n], 0, 0, 0);
    }
}

__device__ __forceinline__ void zero_acc(f32x4 acc[4][4]) {
#pragma unroll
    for (int m = 0; m < 4; m++)
#pragma unroll
        for (int n = 0; n < 4; n++)
#pragma unroll
            for (int q = 0; q < 4; q++) acc[m][n][q] = 0.f;
}

__device__ __forceinline__ const f16* pair_B(const f16* aT, const f16* attT,
                                             int j, int b) {
    if (j == 0) return aT;
    if (j == 3) return aT + 1048576;
    int idx = (j < 3) ? (j - 1) : (j - 2);
    return attT + (size_t)idx * 8388608 + (size_t)b * 1048576;
}

// ================= prep kernels =============================================

// Fused: read x ONCE -> XT[b][(d,l)][v], xT2[b][n][(d,l)], xl[b,d,v]
__global__ __launch_bounds__(256) void k_xtfused(const float* __restrict__ x,
                                                 f16* __restrict__ XT,
                                                 f16* __restrict__ xT2,
                                                 float* __restrict__ xl) {
    __shared__ f16 Ls[64][210];
    int nt = blockIdx.x, d0 = blockIdx.y * 16, b = blockIdx.z;
    int n0 = nt * 64, t = threadIdx.x;
    for (int f = t; f < 3072; f += 256) {
        int dd = f / 192, rem = f - dd * 192, j = rem / 3, q = rem - j * 3;
        float4 v = *reinterpret_cast<const float4*>(
            x + (((size_t)(b * 64 + d0 + dd) * 1024) + n0 + j) * 12 + q * 4);
        f16* dst = &Ls[j][dd * 12 + q * 4];
        dst[0] = (f16)v.x; dst[1] = (f16)v.y; dst[2] = (f16)v.z; dst[3] = (f16)v.w;
    }
    __syncthreads();
    for (int c = t; c < 3072; c += 256) {
        int row = c >> 4, j4 = c & 15;
        int dd = row / 12, l = row - dd * 12;
        f16x4 v;
#pragma unroll
        for (int q = 0; q < 4; q++) v[q] = Ls[j4 * 4 + q][row];
        *reinterpret_cast<f16x4*>(
            &XT[((size_t)(b * 768) + (size_t)(d0 + dd) * 12 + l) * 1024 + n0 + j4 * 4]) = v;
    }
    for (int c = t; c < 1536; c += 256) {
        int j = c / 24, p = c - j * 24;
        *reinterpret_cast<f16x8*>(
            xT2 + ((size_t)(b * 1024) + n0 + j) * 768 + d0 * 12 + p * 8) =
            *reinterpret_cast<const f16x8*>(&Ls[j][p * 8]);
    }
    for (int c = t; c < 1024; c += 256) {
        int dd = c >> 6, j = c & 63;
        float s = 0.f;
#pragma unroll
        for (int l = 0; l < 12; l++) s += (float)Ls[j][dd * 12 + l];
        xl[((size_t)(b * 64 + d0 + dd)) * 1024 + n0 + j] = s;
    }
}

__global__ void k_wcvt(const float* __restrict__ kw, const float* __restrict__ qw,
                       float* __restrict__ kwl, f16* __restrict__ kwb) {
    int i = blockIdx.x * 256 + threadIdx.x;
    int d = i & 63, e = (i >> 6) & 127, var = i >> 13;
    const float* src = (var < 2 ? kw + (size_t)var * 98304
                                : qw + (size_t)(var - 2) * 98304) +
                       ((size_t)e * 64 + d) * 12;
    f16* dst = kwb + ((size_t)var * 128 + e) * 768 + d * 12;
    float ssum = 0.f;
#pragma unroll
    for (int l = 0; l < 12; l++) {
        float v = src[l];
        ssum += v;
        dst[l] = (f16)v;
    }
    kwl[i] = ssum;
}

__global__ void k_tkq(const float* __restrict__ kwl, const float* __restrict__ nv1,
                      const float* __restrict__ nv2, const float* __restrict__ kb,
                      const float* __restrict__ qb, float* __restrict__ tkq) {
    int i = blockIdx.x * 256 + threadIdx.x;
    int e = i & 127, n = (i >> 7) & 1023, var = i >> 17;
    float ssum = (var < 2) ? kb[var * 128 + e] : qb[(var - 2) * 128 + e];
    const float* wl = kwl + ((size_t)var * 128 + e) * 64;
    if (var < 2) {
        const float* nvp = nv1 + (size_t)n * 64;
#pragma unroll 8
        for (int d = 0; d < 64; d++) ssum += wl[d] * nvp[d];
    } else {
#pragma unroll 8
        for (int d = 0; d < 64; d++) ssum += wl[d] * nv2[(size_t)d * 1024 + n];
    }
    tkq[i] = ssum;
}

__global__ void k_acvt(const float* __restrict__ sup, f16* __restrict__ aT) {
    __shared__ float Ls[64][65];
    int s = blockIdx.z, v0 = blockIdx.y * 64, w0 = blockIdx.x * 64, t = threadIdx.x;
    int j = t & 63, i0 = t >> 6;
    for (int i = i0; i < 64; i += 4)
        Ls[i][j] = sup[((size_t)s * 1024 + v0 + i) * 1024 + w0 + j];
    __syncthreads();
    for (int i = i0; i < 64; i += 4)
        aT[((size_t)s * 1024 + w0 + i) * 1024 + v0 + j] = (f16)Ls[j][i];
}

// ================= MFMA GEMM kernels ========================================

// kqgemm (R12 proven form): tile 128x128, grid (8,1,32)
__global__ __launch_bounds__(256) void k_kqgemm(const f16* __restrict__ xT2,
                                                const f16* __restrict__ kwb,
                                                const float* __restrict__ tkq,
                                                f16* __restrict__ keysT) {
    __shared__ char As[16384], Bs[16384];
    int z = blockIdx.z, var = z >> 3, b = z & 7;
    int nt = blockIdx.x, t = threadIdx.x;
    const char* Ag = (const char*)(xT2 + ((size_t)b * 1024 + nt * 128) * 768);
    const char* Bg = (const char*)(kwb + (size_t)var * 128 * 768);
    f32x4 acc[4][4];
    zero_acc(acc);
    for (int kt = 0; kt < 12; kt++) {
        stage_tile(Ag + kt * 128, 1536, As, t);
        stage_tile(Bg + kt * 128, 1536, Bs, t);
        __syncthreads();
        mma_tile(As, Bs, t, acc);
        __syncthreads();
    }
    int lane = t & 63, wid = t >> 6;
    int wr = (wid >> 1) * 64, wc = (wid & 1) * 64;
    int cn = lane & 15, rq = (lane >> 4) * 4;
#pragma unroll
    for (int m = 0; m < 4; m++)
#pragma unroll
        for (int q = 0; q < 4; q++) {
            int n_g = nt * 128 + wr + m * 16 + rq + q;
#pragma unroll
            for (int nn = 0; nn < 4; nn++) {
                int e = wc + nn * 16 + cn;
                float v = acc[m][nn][q] + tkq[((size_t)var * 1024 + n_g) * 128 + e];
                keysT[(((size_t)var * 8 + b) * 1024 + n_g) * 128 + e] = (f16)v;
            }
        }
}

// scTall (f16): [h][b][w][v] = relu(sum_e query[w,e]*keys[v,e]), z = h*8+b
__global__ __launch_bounds__(256) void k_scoregemm2(const f16* __restrict__ keysT,
                                                    f16* __restrict__ scTall) {
    __shared__ char As[16384], Bs[16384];
    int z = blockIdx.z, h = z >> 3, b = z & 7;
    int wt = blockIdx.y, vt = blockIdx.x, t = threadIdx.x;
    const char* Ag = (const char*)(keysT + (((size_t)(2 + h) * 8 + b) * 1024 + wt * 128) * 128);
    const char* Bg = (const char*)(keysT + (((size_t)h * 8 + b) * 1024 + vt * 128) * 128);
    f32x4 acc[4][4];
    zero_acc(acc);
    for (int kt = 0; kt < 2; kt++) {
        stage_tile(Ag + kt * 128, 256, As, t);
        stage_tile(Bg + kt * 128, 256, Bs, t);
        __syncthreads();
        mma_tile(As, Bs, t, acc);
        __syncthreads();
    }
    int lane = t & 63, wid = t >> 6;
    int wr = (wid >> 1) * 64, wc = (wid & 1) * 64;
    int cn = lane & 15, rq = (lane >> 4) * 4;
#pragma unroll
    for (int m = 0; m < 4; m++)
#pragma unroll
        for (int q = 0; q < 4; q++) {
            int w = wt * 128 + wr + m * 16 + rq + q;
#pragma unroll
            for (int nn = 0; nn < 4; nn++) {
                int v = vt * 128 + wc + nn * 16 + cn;
                scTall[((size_t)z * 1024 + w) * 1024 + v] = (f16)fmaxf(acc[m][nn][q], 0.f);
            }
        }
}

// ---- mega prop order-1 (XCD-chunk swizzled, 2304 blocks) ----
__global__ __launch_bounds__(256) void k_prop1m(const f16* __restrict__ ZT,
                                                const f16* __restrict__ aT,
                                                const f16* __restrict__ attT,
                                                f16* __restrict__ P1all) {
    __shared__ char As[16384], Bs[16384];
    int bid = blockIdx.x;
    int swz = (bid & 7) * 288 + (bid >> 3);
    int wt = swz & 7, rt = (swz >> 3) % 6, z = swz / 48;
    int j = z >> 3, b = z & 7;
    int t = threadIdx.x;
    const char* Ag = (const char*)(ZT + ((size_t)b * 768 + rt * 128) * 1024);
    const char* Bg = (const char*)(pair_B(aT, attT, j, b) + (size_t)wt * 128 * 1024);
    f32x4 acc[4][4];
    zero_acc(acc);
    for (int kt = 0; kt < 16; kt++) {
        stage_tile(Ag + kt * 128, 2048, As, t);
        stage_tile(Bg + kt * 128, 2048, Bs, t);
        __syncthreads();
        mma_tile(As, Bs, t, acc);
        __syncthreads();
    }
    f16* P1 = P1all + (size_t)j * 6291456;
    int lane = t & 63, wid = t >> 6;
    int wr = (wid >> 1) * 64, wc = (wid & 1) * 64;
    int cn = lane & 15, rq = (lane >> 4) * 4;
#pragma unroll
    for (int m = 0; m < 4; m++)
#pragma unroll
        for (int q = 0; q < 4; q++) {
            int r = rt * 128 + wr + m * 16 + rq + q;
            size_t pbase = ((size_t)b * 768 + r) * 1024;
#pragma unroll
            for (int nn = 0; nn < 4; nn++) {
                int w = wt * 128 + wc + nn * 16 + cn;
                P1[pbase + w] = (f16)acc[m][nn][q];
            }
        }
}

// ---- mega prop order-2: P2all[j] = P1all[j] . M[j] ----
__global__ __launch_bounds__(256) void k_prop2m(const f16* __restrict__ P1all,
                                                const f16* __restrict__ aT,
                                                const f16* __restrict__ attT,
                                                f16* __restrict__ P2all) {
    __shared__ char As[16384], Bs[16384];
    int bid = blockIdx.x;
    int swz = (bid & 7) * 288 + (bid >> 3);
    int wt = swz & 7, rt = (swz >> 3) % 6, z = swz / 48;
    int j = z >> 3, b = z & 7;
    int t = threadIdx.x;
    const char* Ag = (const char*)(P1all + (size_t)j * 6291456 +
                                   ((size_t)b * 768 + rt * 128) * 1024);
    const char* Bg = (const char*)(pair_B(aT, attT, j, b) + (size_t)wt * 128 * 1024);
    f32x4 acc[4][4];
    zero_acc(acc);
    for (int kt = 0; kt < 16; kt++) {
        stage_tile(Ag + kt * 128, 2048, As, t);
        stage_tile(Bg + kt * 128, 2048, Bs, t);
        __syncthreads();
        mma_tile(As, Bs, t, acc);
        __syncthreads();
    }
    f16* P2 = P2all + (size_t)j * 6291456;
    int lane = t & 63, wid = t >> 6;
    int wr = (wid >> 1) * 64, wc = (wid & 1) * 64;
    int cn = lane & 15, rq = (lane >> 4) * 4;
#pragma unroll
    for (int m = 0; m < 4; m++)
#pragma unroll
        for (int q = 0; q < 4; q++) {
            int r = rt * 128 + wr + m * 16 + rq + q;
            size_t pbase = ((size_t)b * 768 + r) * 1024;
#pragma unroll
            for (int nn = 0; nn < 4; nn++) {
                int w = wt * 128 + wc + nn * 16 + cn;
                P2[pbase + w] = (f16)acc[m][nn][q];
            }
        }
}

// ================= softmax / stats / gate ===================================

// vectorized: lane owns 16 contiguous v (f16x8 loads/stores)
__global__ void k_softmax3(const f16* __restrict__ scTall, const f16* __restrict__ aT,
                           f16* __restrict__ attT) {
    int gw = blockIdx.x * 4 + (threadIdx.x >> 6);
    int w = gw & 1023, hb = gw >> 10;
    int h = hb >> 3, b = hb & 7;
    int lane = threadIdx.x & 63;
    const f16* sp = scTall + (size_t)gw * 1024 + lane * 16;
    f16x8 e0 = *reinterpret_cast<const f16x8*>(sp);
    f16x8 e1 = *reinterpret_cast<const f16x8*>(sp + 8);
#pragma unroll
    for (int s = 0; s < 2; s++) {
        const f16* ap = aT + ((size_t)s * 1024 + w) * 1024 + lane * 16;
        f16x8 a0 = *reinterpret_cast<const f16x8*>(ap);
        f16x8 a1 = *reinterpret_cast<const f16x8*>(ap + 8);
        float xx[16];
        float m = NEGV;
#pragma unroll
        for (int k = 0; k < 8; k++) {
            xx[k]     = ((float)a0[k] > 0.f) ? (float)e0[k] : NEGV;
            xx[8 + k] = ((float)a1[k] > 0.f) ? (float)e1[k] : NEGV;
        }
#pragma unroll
        for (int k = 0; k < 16; k++) m = fmaxf(m, xx[k]);
#pragma unroll
        for (int off = 1; off < 64; off <<= 1) m = fmaxf(m, __shfl_xor(m, off));
        float ssum = 0.f;
#pragma unroll
        for (int k = 0; k < 16; k++) {
            xx[k] = __expf(xx[k] - m);
            ssum += xx[k];
        }
#pragma unroll
        for (int off = 1; off < 64; off <<= 1) ssum += __shfl_xor(ssum, off);
        float inv = 1.f / ssum;
        f16x8 o0, o1;
#pragma unroll
        for (int k = 0; k < 8; k++) {
            o0[k] = (f16)(xx[k] * inv);
            o1[k] = (f16)(xx[8 + k] * inv);
        }
        f16* op = attT + (size_t)(s * 2 + h) * 8388608 +
                  ((size_t)b * 1024 + w) * 1024 + lane * 16;
        *reinterpret_cast<f16x8*>(op) = o0;
        *reinterpret_cast<f16x8*>(op + 8) = o1;
    }
}

template <int ORDER>
__global__ __launch_bounds__(256) void k_colsum1(
    const f16* __restrict__ aT, const f16* __restrict__ attT,
    const float* __restrict__ ra, const float* __restrict__ ratt,
    float* __restrict__ partial) {
    int u = blockIdx.y, rc = blockIdx.x;
    int t = threadIdx.x;
    int lane7 = t & 127, rh = t >> 7;
    int v0 = lane7 * 8;
    const f16* M = (u < 2) ? aT + (size_t)u * 1048576
                           : attT + (size_t)(u - 2) * 1048576;
    const float* rin = nullptr;
    if (ORDER) rin = (u < 2) ? ra + (size_t)u * 2048 : ratt + (size_t)(u - 2) * 2048;
    float acc[8] = {};
    int row0 = rc * 64 + rh * 32;
#pragma unroll 4
    for (int i = 0; i < 32; i++) {
        int row = row0 + i;
        f16x8 mv = *reinterpret_cast<const f16x8*>(M + (size_t)row * 1024 + v0);
        float sc = ORDER ? rin[row] : 1.f;
#pragma unroll
        for (int j = 0; j < 8; j++) acc[j] += (float)mv[j] * sc;
    }
    float4* pp = reinterpret_cast<float4*>(
        partial + ((size_t)u * 32 + rc * 2 + rh) * 1024 + v0);
    float4 w0 = {acc[0], acc[1], acc[2], acc[3]};
    float4 w1 = {acc[4], acc[5], acc[6], acc[7]};
    pp[0] = w0; pp[1] = w1;
}

template <int ORDER>
__global__ void k_colsum2(const float* __restrict__ partial, float* __restrict__ ra,
                          float* __restrict__ ratt) {
    int u = blockIdx.x, t = threadIdx.x;
    for (int v = t; v < 1024; v += 256) {
        float s = 0.f;
#pragma unroll
        for (int k = 0; k < 32; k++) s += partial[((size_t)u * 32 + k) * 1024 + v];
        float* out = (u < 2) ? ra + (size_t)u * 2048 : ratt + (size_t)(u - 2) * 2048;
        out[ORDER * 1024 + v] = s;
    }
}

__global__ void k_feat13(const float* __restrict__ xl, const float* __restrict__ ra,
                         const float* __restrict__ ratt, float* __restrict__ feats) {
    int bd = blockIdx.x;
    int b = bd >> 6, d = bd & 63;
    const float* xp = xl + (size_t)bd * 1024;
    int t = threadIdx.x;
    float s[13];
#pragma unroll
    for (int i = 0; i < 13; i++) s[i] = 0.f;
    for (int v = t; v < 1024; v += 256) {
        float xv = xp[v];
        s[0] += xv;
#pragma unroll
        for (int ss = 0; ss < 2; ss++) {
            s[1 + ss * 6 + 0] += xv * ra[ss * 2048 + v];
            s[1 + ss * 6 + 1] += xv * ra[ss * 2048 + 1024 + v];
#pragma unroll
            for (int hh = 0; hh < 2; hh++) {
                const float* rb = ratt + (((size_t)(ss * 2 + hh) * 8 + b)) * 2048;
                s[1 + ss * 6 + 2 + hh * 2] += xv * rb[v];
                s[1 + ss * 6 + 3 + hh * 2] += xv * rb[1024 + v];
            }
        }
    }
    int wid = t >> 6, lane = t & 63;
#pragma unroll
    for (int i = 0; i < 13; i++)
#pragma unroll
        for (int off = 1; off < 64; off <<= 1) s[i] += __shfl_xor(s[i], off);
    __shared__ float red[13][4];
    if (lane == 0)
#pragma unroll
        for (int i = 0; i < 13; i++) red[i][wid] = s[i];
    __syncthreads();
    if (t < 13) {
        float tot = red[t][0] + red[t][1] + red[t][2] + red[t][3];
        feats[(size_t)b * 832 + t * 64 + d] = tot * (1.f / (1024.f * 12.f));
    }
}

__global__ void k_gate(const float* __restrict__ feats, const float* __restrict__ aw,
                       const float* __restrict__ ab, float* __restrict__ gate) {
    int b = blockIdx.x, t = threadIdx.x;
    __shared__ float lg[13];
    if (t < 13) {
        float s = ab[t];
        const float* f = feats + (size_t)b * 832;
        const float* w = aw + (size_t)t * 832;
        for (int k = 0; k < 832; k++) s += f[k] * w[k];
        lg[t] = s;
    }
    __syncthreads();
    if (t == 0) {
        float m = lg[0];
        for (int j = 1; j < 13; j++) m = fmaxf(m, lg[j]);
        float ss = 0.f;
        for (int j = 0; j < 13; j++) ss += __expf(lg[j] - m);
        float inv = 1.f / ss;
        for (int j = 0; j < 13; j++) gate[b * 13 + j] = __expf(lg[j] - m) * inv;
    }
}

// ---------- z-projection, in place on XT, LDS-staged ----------
__global__ __launch_bounds__(256) void k_zt2(f16* __restrict__ XT,
                                             const float* __restrict__ fw) {
    __shared__ f16 xs[64][136];
    __shared__ float fws[64][64];
    int nt = blockIdx.x, l = blockIdx.y, b = blockIdx.z;
    int t = threadIdx.x;
    f16* base = XT + (size_t)b * 786432 + (size_t)l * 1024 + nt * 128;
#pragma unroll
    for (int it = 0; it < 4; it++) {
        int idx = it * 256 + t;
        int row = idx >> 4, c = idx & 15;
        *reinterpret_cast<f16x8*>(&xs[row][c * 8]) =
            *reinterpret_cast<const f16x8*>(base + (size_t)row * 12288 + c * 8);
    }
    for (int i = t; i < 4096; i += 256) ((float*)fws)[i] = fw[i];
    __syncthreads();
    int nl = t & 31, og = t >> 5;
    float acc[8][4];
#pragma unroll
    for (int oo = 0; oo < 8; oo++)
#pragma unroll
        for (int j = 0; j < 4; j++) acc[oo][j] = 0.f;
#pragma unroll 4
    for (int d = 0; d < 64; d++) {
        f16x4 xv = *reinterpret_cast<const f16x4*>(&xs[d][nl * 4]);
        float x0 = (float)xv[0], x1 = (float)xv[1], x2 = (float)xv[2], x3 = (float)xv[3];
#pragma unroll
        for (int oo = 0; oo < 8; oo++) {
            float w = fws[og * 8 + oo][d];
            acc[oo][0] += w * x0; acc[oo][1] += w * x1;
            acc[oo][2] += w * x2; acc[oo][3] += w * x3;
        }
    }
#pragma unroll
    for (int oo = 0; oo < 8; oo++) {
        int o = og * 8 + oo;
        f16x4 ov;
        ov[0] = (f16)acc[oo][0]; ov[1] = (f16)acc[oo][1];
        ov[2] = (f16)acc[oo][2]; ov[3] = (f16)acc[oo][3];
        *reinterpret_cast<f16x4*>(base + (size_t)o * 12288 + nl * 4) = ov;
    }
}

// ---- final: out = fb + g0*Z + sum_j (g1j*P1[j] + g2j*P2[j]); 2 n per thread ----
__global__ void k_out(const f16* __restrict__ ZT, const f16* __restrict__ P1all,
                      const f16* __restrict__ P2all, const float* __restrict__ gate,
                      const float* __restrict__ fb, float* __restrict__ out) {
    int idx = blockIdx.x * 256 + threadIdx.x;     // (b,o,n2)
    int n2 = idx & 511, o = (idx >> 9) & 63, b = idx >> 15;
    int n = n2 * 2;
    const float* g = gate + b * 13;
    size_t rowbase = ((size_t)b * 768 + o * 12) * 1024 + n;
    float g0 = g[0], fbv = fb[o];
    float v0[12], v1[12];
#pragma unroll
    for (int l = 0; l < 12; l++) {
        f16x2 z2 = *reinterpret_cast<const f16x2*>(&ZT[rowbase + (size_t)l * 1024]);
        v0[l] = fbv + g0 * (float)z2[0];
        v1[l] = fbv + g0 * (float)z2[1];
    }
#pragma unroll
    for (int j = 0; j < 6; j++) {
        float g1 = g[1 + 2 * j], g2 = g[2 + 2 * j];
        const f16* p1 = P1all + (size_t)j * 6291456 + rowbase;
        const f16* p2 = P2all + (size_t)j * 6291456 + rowbase;
#pragma unroll
        for (int l = 0; l < 12; l++) {
            f16x2 a2 = *reinterpret_cast<const f16x2*>(&p1[(size_t)l * 1024]);
            f16x2 b2 = *reinterpret_cast<const f16x2*>(&p2[(size_t)l * 1024]);
            v0[l] += g1 * (float)a2[0] + g2 * (float)b2[0];
            v1[l] += g1 * (float)a2[1] + g2 * (float)b2[1];
        }
    }
    float4* dst0 = reinterpret_cast<float4*>(out + (((size_t)b * 64 + o) * 1024 + n) * 12);
    float4 a0 = {v0[0], v0[1], v0[2], v0[3]};
    float4 a1 = {v0[4], v0[5], v0[6], v0[7]};
    float4 a2 = {v0[8], v0[9], v0[10], v0[11]};
    dst0[0] = a0; dst0[1] = a1; dst0[2] = a2;
    float4 b0 = {v1[0], v1[1], v1[2], v1[3]};
    float4 b1 = {v1[4], v1[5], v1[6], v1[7]};
    float4 b2 = {v1[8], v1[9], v1[10], v1[11]};
    dst0[3] = b0; dst0[4] = b1; dst0[5] = b2;
}

// ================= launch ===================================================

extern "C" void kernel_launch(void* const* d_in, const int* in_sizes, int n_in,
                              void* d_out, int out_size, void* d_ws, size_t ws_size,
                              hipStream_t stream) {
    const float* x   = (const float*)d_in[0];
    const float* sup = (const float*)d_in[1];
    const float* nv1 = (const float*)d_in[2];
    const float* nv2 = (const float*)d_in[3];
    const float* kw  = (const float*)d_in[4];
    const float* kb  = (const float*)d_in[5];
    const float* qw  = (const float*)d_in[6];
    const float* qb  = (const float*)d_in[7];
    const float* aw  = (const float*)d_in[8];
    const float* ab  = (const float*)d_in[9];
    const float* fw  = (const float*)d_in[10];
    const float* fb  = (const float*)d_in[11];
    float* hout = (float*)d_out;

    float* wsf = (float*)d_ws;
    size_t o = 0;
    f16*   XT     = (f16*)(wsf + o);  o += 3145728;
    float* attReg = wsf + o;          o += 16777216;
    f16*   attT   = (f16*)attReg;
    f16*   xT2    = (f16*)attReg;
    f16*   aT     = (f16*)(wsf + o);  o += 1048576;
    float* gate   = wsf + o;          o += 128;
    size_t rc = o;
    // ---- phase A ----
    size_t oA = rc;
    f16*   scTall = (f16*)(wsf + oA);  oA += 8388608;
    f16*   keysT  = (f16*)(wsf + oA);  oA += 2097152;
    f16*   kwb    = (f16*)(wsf + oA);  oA += 196608;
    float* kwl    = wsf + oA;          oA += 32768;
    float* tkq    = wsf + oA;          oA += 524288;
    float* xl     = wsf + oA;          oA += 524288;
    float* ra     = wsf + oA;          oA += 4096;
    float* ratt   = wsf + oA;          oA += 65536;
    float* feats  = wsf + oA;          oA += 6656;
    float* partial= wsf + oA;          oA += 1114112;
    // ---- phase B ----
    size_t oB = rc;
    f16*   P1all  = (f16*)(wsf + oB); oB += 18874368;
    f16*   P2all  = (f16*)(wsf + oB); oB += 18874368;
    size_t need = ((oA > oB) ? oA : oB) * 4;
    if (ws_size < need) return;

    f16* ZT = XT;

    k_xtfused<<<dim3(16, 4, 8), 256, 0, stream>>>(x, XT, xT2, xl);
    k_wcvt<<<128, 256, 0, stream>>>(kw, qw, kwl, kwb);
    k_tkq<<<2048, 256, 0, stream>>>(kwl, nv1, nv2, kb, qb, tkq);
    k_acvt<<<dim3(16, 16, 2), 256, 0, stream>>>(sup, aT);

    k_kqgemm<<<dim3(8, 1, 32), 256, 0, stream>>>(xT2, kwb, tkq, keysT);

    k_scoregemm2<<<dim3(8, 8, 16), 256, 0, stream>>>(keysT, scTall);
    k_softmax3<<<4096, 256, 0, stream>>>(scTall, aT, attT);

    k_colsum1<0><<<dim3(16, 34), 256, 0, stream>>>(aT, attT, ra, ratt, partial);
    k_colsum2<0><<<34, 256, 0, stream>>>(partial, ra, ratt);
    k_colsum1<1><<<dim3(16, 34), 256, 0, stream>>>(aT, attT, ra, ratt, partial);
    k_colsum2<1><<<34, 256, 0, stream>>>(partial, ra, ratt);
    k_feat13<<<512, 256, 0, stream>>>(xl, ra, ratt, feats);
    k_gate<<<8, 64, 0, stream>>>(feats, aw, ab, gate);

    k_zt2<<<dim3(8, 12, 8), 256, 0, stream>>>(XT, fw);

    k_prop1m<<<2304, 256, 0, stream>>>(ZT, aT, attT, P1all);
    k_prop2m<<<2304, 256, 0, stream>>>(P1all, aT, attT, P2all);
    k_out<<<1024, 256, 0, stream>>>(ZT, P1all, P2all, gate, fb, hout);
}

// Round 15
// 369.747 us; speedup vs baseline: 1.1109x; 1.1109x over previous
//
#include <hip/hip_runtime.h>
#include <hip/hip_bf16.h>

#define BB 8
#define DD 64
#define NNODE 1024
#define LLL 12
#define EE 128
#define NEGV -9.0e15f

typedef _Float16 f16;
typedef _Float16 f16x4 __attribute__((ext_vector_type(4)));
typedef _Float16 f16x8 __attribute__((ext_vector_type(8)));
typedef float f32x4 __attribute__((ext_vector_type(4)));

// ================= 128^2 GEMM core helpers ==================================

__device__ __forceinline__ void stage_tile(const char* g, int ld, char* lds, int t) {
    int wid = t >> 6, lane = t & 63;
#pragma unroll
    for (int it = 0; it < 4; it++) {
        int cbase = it * 256 + wid * 64;
        int c = cbase + lane;
        int row = c >> 3, p = c & 7;
        int gch = p ^ (row & 7);
        const char* src = g + (size_t)row * ld + gch * 16;
        char* dst = lds + (size_t)cbase * 16;
        __builtin_amdgcn_global_load_lds(
            (const __attribute__((address_space(1))) unsigned int*)src,
            (__attribute__((address_space(3))) unsigned int*)dst, 16, 0, 0);
    }
}

__device__ __forceinline__ void mma_tile(const char* As, const char* Bs, int t,
                                         f32x4 acc[4][4]) {
    int lane = t & 63, wid = t >> 6;
    int wr = (wid >> 1) * 64, wc = (wid & 1) * 64;
    int lrow = lane & 15, lk = lane >> 4;
#pragma unroll
    for (int kk = 0; kk < 2; kk++) {
        f16x8 af[4], bf[4];
#pragma unroll
        for (int m = 0; m < 4; m++) {
            int row = wr + m * 16 + lrow;
            int p = (kk * 4 + lk) ^ (row & 7);
            af[m] = *(const f16x8*)(As + row * 128 + p * 16);
        }
#pragma unroll
        for (int n = 0; n < 4; n++) {
            int row = wc + n * 16 + lrow;
            int p = (kk * 4 + lk) ^ (row & 7);
            bf[n] = *(const f16x8*)(Bs + row * 128 + p * 16);
        }
#pragma unroll
        for (int m = 0; m < 4; m++)
#pragma unroll
            for (int n = 0; n < 4; n++)
                acc[m][n] = __builtin_amdgcn_mfma_f32_16x16x32_f16(
                    af[m], bf[n], acc[m][n], 0, 0, 0);
    }
}

__device__ __forceinline__ void zero_acc(f32x4 acc[4][4]) {
#pragma unroll
    for (int m = 0; m < 4; m++)
#pragma unroll
        for (int n = 0; n < 4; n++)
#pragma unroll
            for (int q = 0; q < 4; q++) acc[m][n][q] = 0.f;
}

__device__ __forceinline__ const f16* pair_B(const f16* aT, const f16* attT,
                                             int j, int b) {
    if (j == 0) return aT;
    if (j == 3) return aT + 1048576;
    int idx = (j < 3) ? (j - 1) : (j - 2);
    return attT + (size_t)idx * 8388608 + (size_t)b * 1048576;
}

// ================= prep kernels =============================================

// Fused: read x ONCE -> XT[b][(d,l)][v], xT2[b][n][(d,l)], xl[b,d,v]
__global__ __launch_bounds__(256) void k_xtfused(const float* __restrict__ x,
                                                 f16* __restrict__ XT,
                                                 f16* __restrict__ xT2,
                                                 float* __restrict__ xl) {
    __shared__ f16 Ls[64][210];
    int nt = blockIdx.x, d0 = blockIdx.y * 16, b = blockIdx.z;
    int n0 = nt * 64, t = threadIdx.x;
    for (int f = t; f < 3072; f += 256) {
        int dd = f / 192, rem = f - dd * 192, j = rem / 3, q = rem - j * 3;
        float4 v = *reinterpret_cast<const float4*>(
            x + (((size_t)(b * 64 + d0 + dd) * 1024) + n0 + j) * 12 + q * 4);
        f16* dst = &Ls[j][dd * 12 + q * 4];
        dst[0] = (f16)v.x; dst[1] = (f16)v.y; dst[2] = (f16)v.z; dst[3] = (f16)v.w;
    }
    __syncthreads();
    // XT: 192 rows (dd,l) x 64 n, coalesced scalar writes (measured-good form)
    for (int c = t; c < 12288; c += 256) {
        int row = c >> 6, j = c & 63;
        int dd = row / 12, l = row - dd * 12;
        XT[((size_t)(b * 768) + (size_t)(d0 + dd) * 12 + l) * 1024 + n0 + j] =
            Ls[j][row];
    }
    for (int c = t; c < 1536; c += 256) {
        int j = c / 24, p = c - j * 24;
        *reinterpret_cast<f16x8*>(
            xT2 + ((size_t)(b * 1024) + n0 + j) * 768 + d0 * 12 + p * 8) =
            *reinterpret_cast<const f16x8*>(&Ls[j][p * 8]);
    }
    for (int c = t; c < 1024; c += 256) {
        int dd = c >> 6, j = c & 63;
        float s = 0.f;
#pragma unroll
        for (int l = 0; l < 12; l++) s += (float)Ls[j][dd * 12 + l];
        xl[((size_t)(b * 64 + d0 + dd)) * 1024 + n0 + j] = s;
    }
}

__global__ void k_wcvt(const float* __restrict__ kw, const float* __restrict__ qw,
                       float* __restrict__ kwl, f16* __restrict__ kwb) {
    int i = blockIdx.x * 256 + threadIdx.x;
    int d = i & 63, e = (i >> 6) & 127, var = i >> 13;
    const float* src = (var < 2 ? kw + (size_t)var * 98304
                                : qw + (size_t)(var - 2) * 98304) +
                       ((size_t)e * 64 + d) * 12;
    f16* dst = kwb + ((size_t)var * 128 + e) * 768 + d * 12;
    float ssum = 0.f;
#pragma unroll
    for (int l = 0; l < 12; l++) {
        float v = src[l];
        ssum += v;
        dst[l] = (f16)v;
    }
    kwl[i] = ssum;
}

__global__ void k_tkq(const float* __restrict__ kwl, const float* __restrict__ nv1,
                      const float* __restrict__ nv2, const float* __restrict__ kb,
                      const float* __restrict__ qb, float* __restrict__ tkq) {
    int i = blockIdx.x * 256 + threadIdx.x;
    int e = i & 127, n = (i >> 7) & 1023, var = i >> 17;
    float ssum = (var < 2) ? kb[var * 128 + e] : qb[(var - 2) * 128 + e];
    const float* wl = kwl + ((size_t)var * 128 + e) * 64;
    if (var < 2) {
        const float* nvp = nv1 + (size_t)n * 64;
#pragma unroll 8
        for (int d = 0; d < 64; d++) ssum += wl[d] * nvp[d];
    } else {
#pragma unroll 8
        for (int d = 0; d < 64; d++) ssum += wl[d] * nv2[(size_t)d * 1024 + n];
    }
    tkq[i] = ssum;
}

__global__ void k_acvt(const float* __restrict__ sup, f16* __restrict__ aT) {
    __shared__ float Ls[64][65];
    int s = blockIdx.z, v0 = blockIdx.y * 64, w0 = blockIdx.x * 64, t = threadIdx.x;
    int j = t & 63, i0 = t >> 6;
    for (int i = i0; i < 64; i += 4)
        Ls[i][j] = sup[((size_t)s * 1024 + v0 + i) * 1024 + w0 + j];
    __syncthreads();
    for (int i = i0; i < 64; i += 4)
        aT[((size_t)s * 1024 + w0 + i) * 1024 + v0 + j] = (f16)Ls[j][i];
}

// ================= MFMA GEMM kernels ========================================

__global__ __launch_bounds__(256) void k_kqgemm(const f16* __restrict__ xT2,
                                                const f16* __restrict__ kwb,
                                                const float* __restrict__ tkq,
                                                f16* __restrict__ keysT) {
    __shared__ char As[16384], Bs[16384];
    int z = blockIdx.z, var = z >> 3, b = z & 7;
    int nt = blockIdx.x, t = threadIdx.x;
    const char* Ag = (const char*)(xT2 + ((size_t)b * 1024 + nt * 128) * 768);
    const char* Bg = (const char*)(kwb + (size_t)var * 128 * 768);
    f32x4 acc[4][4];
    zero_acc(acc);
    for (int kt = 0; kt < 12; kt++) {
        stage_tile(Ag + kt * 128, 1536, As, t);
        stage_tile(Bg + kt * 128, 1536, Bs, t);
        __syncthreads();
        mma_tile(As, Bs, t, acc);
        __syncthreads();
    }
    int lane = t & 63, wid = t >> 6;
    int wr = (wid >> 1) * 64, wc = (wid & 1) * 64;
    int cn = lane & 15, rq = (lane >> 4) * 4;
#pragma unroll
    for (int m = 0; m < 4; m++)
#pragma unroll
        for (int q = 0; q < 4; q++) {
            int n_g = nt * 128 + wr + m * 16 + rq + q;
#pragma unroll
            for (int nn = 0; nn < 4; nn++) {
                int e = wc + nn * 16 + cn;
                float v = acc[m][nn][q] + tkq[((size_t)var * 1024 + n_g) * 128 + e];
                keysT[(((size_t)var * 8 + b) * 1024 + n_g) * 128 + e] = (f16)v;
            }
        }
}

// scTall (f16): [h][b][w][v] = relu(sum_e query[w,e]*keys[v,e]), z = h*8+b
__global__ __launch_bounds__(256) void k_scoregemm2(const f16* __restrict__ keysT,
                                                    f16* __restrict__ scTall) {
    __shared__ char As[16384], Bs[16384];
    int z = blockIdx.z, h = z >> 3, b = z & 7;
    int wt = blockIdx.y, vt = blockIdx.x, t = threadIdx.x;
    const char* Ag = (const char*)(keysT + (((size_t)(2 + h) * 8 + b) * 1024 + wt * 128) * 128);
    const char* Bg = (const char*)(keysT + (((size_t)h * 8 + b) * 1024 + vt * 128) * 128);
    f32x4 acc[4][4];
    zero_acc(acc);
    for (int kt = 0; kt < 2; kt++) {
        stage_tile(Ag + kt * 128, 256, As, t);
        stage_tile(Bg + kt * 128, 256, Bs, t);
        __syncthreads();
        mma_tile(As, Bs, t, acc);
        __syncthreads();
    }
    int lane = t & 63, wid = t >> 6;
    int wr = (wid >> 1) * 64, wc = (wid & 1) * 64;
    int cn = lane & 15, rq = (lane >> 4) * 4;
#pragma unroll
    for (int m = 0; m < 4; m++)
#pragma unroll
        for (int q = 0; q < 4; q++) {
            int w = wt * 128 + wr + m * 16 + rq + q;
#pragma unroll
            for (int nn = 0; nn < 4; nn++) {
                int v = vt * 128 + wc + nn * 16 + cn;
                scTall[((size_t)z * 1024 + w) * 1024 + v] = (f16)fmaxf(acc[m][nn][q], 0.f);
            }
        }
}

// ---- mega prop order-1 (XCD-chunk swizzled, 2304 blocks) ----
__global__ __launch_bounds__(256) void k_prop1m(const f16* __restrict__ ZT,
                                                const f16* __restrict__ aT,
                                                const f16* __restrict__ attT,
                                                f16* __restrict__ P1all) {
    __shared__ char As[16384], Bs[16384];
    int bid = blockIdx.x;
    int swz = (bid & 7) * 288 + (bid >> 3);
    int wt = swz & 7, rt = (swz >> 3) % 6, z = swz / 48;
    int j = z >> 3, b = z & 7;
    int t = threadIdx.x;
    const char* Ag = (const char*)(ZT + ((size_t)b * 768 + rt * 128) * 1024);
    const char* Bg = (const char*)(pair_B(aT, attT, j, b) + (size_t)wt * 128 * 1024);
    f32x4 acc[4][4];
    zero_acc(acc);
    for (int kt = 0; kt < 16; kt++) {
        stage_tile(Ag + kt * 128, 2048, As, t);
        stage_tile(Bg + kt * 128, 2048, Bs, t);
        __syncthreads();
        mma_tile(As, Bs, t, acc);
        __syncthreads();
    }
    f16* P1 = P1all + (size_t)j * 6291456;
    int lane = t & 63, wid = t >> 6;
    int wr = (wid >> 1) * 64, wc = (wid & 1) * 64;
    int cn = lane & 15, rq = (lane >> 4) * 4;
#pragma unroll
    for (int m = 0; m < 4; m++)
#pragma unroll
        for (int q = 0; q < 4; q++) {
            int r = rt * 128 + wr + m * 16 + rq + q;
            size_t pbase = ((size_t)b * 768 + r) * 1024;
#pragma unroll
            for (int nn = 0; nn < 4; nn++) {
                int w = wt * 128 + wc + nn * 16 + cn;
                P1[pbase + w] = (f16)acc[m][nn][q];
            }
        }
}

// ---- mega prop order-2: P2all[j] = P1all[j] . M[j] ----
__global__ __launch_bounds__(256) void k_prop2m(const f16* __restrict__ P1all,
                                                const f16* __restrict__ aT,
                                                const f16* __restrict__ attT,
                                                f16* __restrict__ P2all) {
    __shared__ char As[16384], Bs[16384];
    int bid = blockIdx.x;
    int swz = (bid & 7) * 288 + (bid >> 3);
    int wt = swz & 7, rt = (swz >> 3) % 6, z = swz / 48;
    int j = z >> 3, b = z & 7;
    int t = threadIdx.x;
    const char* Ag = (const char*)(P1all + (size_t)j * 6291456 +
                                   ((size_t)b * 768 + rt * 128) * 1024);
    const char* Bg = (const char*)(pair_B(aT, attT, j, b) + (size_t)wt * 128 * 1024);
    f32x4 acc[4][4];
    zero_acc(acc);
    for (int kt = 0; kt < 16; kt++) {
        stage_tile(Ag + kt * 128, 2048, As, t);
        stage_tile(Bg + kt * 128, 2048, Bs, t);
        __syncthreads();
        mma_tile(As, Bs, t, acc);
        __syncthreads();
    }
    f16* P2 = P2all + (size_t)j * 6291456;
    int lane = t & 63, wid = t >> 6;
    int wr = (wid >> 1) * 64, wc = (wid & 1) * 64;
    int cn = lane & 15, rq = (lane >> 4) * 4;
#pragma unroll
    for (int m = 0; m < 4; m++)
#pragma unroll
        for (int q = 0; q < 4; q++) {
            int r = rt * 128 + wr + m * 16 + rq + q;
            size_t pbase = ((size_t)b * 768 + r) * 1024;
#pragma unroll
            for (int nn = 0; nn < 4; nn++) {
                int w = wt * 128 + wc + nn * 16 + cn;
                P2[pbase + w] = (f16)acc[m][nn][q];
            }
        }
}

// ================= softmax / stats / gate ===================================

__global__ void k_softmax3(const f16* __restrict__ scTall, const f16* __restrict__ aT,
                           f16* __restrict__ attT) {
    int gw = blockIdx.x * 4 + (threadIdx.x >> 6);
    int w = gw & 1023, hb = gw >> 10;
    int h = hb >> 3, b = hb & 7;
    int lane = threadIdx.x & 63;
    const f16* sp = scTall + (size_t)gw * 1024;
    float e[16];
#pragma unroll
    for (int k = 0; k < 16; k++) e[k] = (float)sp[k * 64 + lane];
#pragma unroll
    for (int s = 0; s < 2; s++) {
        const f16* ap = aT + ((size_t)s * 1024 + w) * 1024;
        float xx[16];
        float m = NEGV;
#pragma unroll
        for (int k = 0; k < 16; k++) {
            int v = k * 64 + lane;
            xx[k] = ((float)ap[v] > 0.f) ? e[k] : NEGV;
            m = fmaxf(m, xx[k]);
        }
#pragma unroll
        for (int off = 1; off < 64; off <<= 1) m = fmaxf(m, __shfl_xor(m, off));
        float ssum = 0.f;
#pragma unroll
        for (int k = 0; k < 16; k++) {
            xx[k] = __expf(xx[k] - m);
            ssum += xx[k];
        }
#pragma unroll
        for (int off = 1; off < 64; off <<= 1) ssum += __shfl_xor(ssum, off);
        float inv = 1.f / ssum;
        f16* op = attT + (size_t)(s * 2 + h) * 8388608 +
                  ((size_t)b * 1024 + w) * 1024;
#pragma unroll
        for (int k = 0; k < 16; k++) op[k * 64 + lane] = (f16)(xx[k] * inv);
    }
}

template <int ORDER>
__global__ __launch_bounds__(256) void k_colsum1(
    const f16* __restrict__ aT, const f16* __restrict__ attT,
    const float* __restrict__ ra, const float* __restrict__ ratt,
    float* __restrict__ partial) {
    int u = blockIdx.y, rc = blockIdx.x;
    int t = threadIdx.x;
    int lane7 = t & 127, rh = t >> 7;
    int v0 = lane7 * 8;
    const f16* M = (u < 2) ? aT + (size_t)u * 1048576
                           : attT + (size_t)(u - 2) * 1048576;
    const float* rin = nullptr;
    if (ORDER) rin = (u < 2) ? ra + (size_t)u * 2048 : ratt + (size_t)(u - 2) * 2048;
    float acc[8] = {};
    int row0 = rc * 64 + rh * 32;
#pragma unroll 4
    for (int i = 0; i < 32; i++) {
        int row = row0 + i;
        f16x8 mv = *reinterpret_cast<const f16x8*>(M + (size_t)row * 1024 + v0);
        float sc = ORDER ? rin[row] : 1.f;
#pragma unroll
        for (int j = 0; j < 8; j++) acc[j] += (float)mv[j] * sc;
    }
    float* pp = partial + ((size_t)u * 32 + rc * 2 + rh) * 1024 + v0;
#pragma unroll
    for (int j = 0; j < 8; j++) pp[j] = acc[j];
}

template <int ORDER>
__global__ void k_colsum2(const float* __restrict__ partial, float* __restrict__ ra,
                          float* __restrict__ ratt) {
    int u = blockIdx.x, t = threadIdx.x;
    for (int v = t; v < 1024; v += 256) {
        float s = 0.f;
#pragma unroll
        for (int k = 0; k < 32; k++) s += partial[((size_t)u * 32 + k) * 1024 + v];
        float* out = (u < 2) ? ra + (size_t)u * 2048 : ratt + (size_t)(u - 2) * 2048;
        out[ORDER * 1024 + v] = s;
    }
}

__global__ void k_feat13(const float* __restrict__ xl, const float* __restrict__ ra,
                         const float* __restrict__ ratt, float* __restrict__ feats) {
    int bd = blockIdx.x;
    int b = bd >> 6, d = bd & 63;
    const float* xp = xl + (size_t)bd * 1024;
    int t = threadIdx.x;
    float s[13];
#pragma unroll
    for (int i = 0; i < 13; i++) s[i] = 0.f;
    for (int v = t; v < 1024; v += 256) {
        float xv = xp[v];
        s[0] += xv;
#pragma unroll
        for (int ss = 0; ss < 2; ss++) {
            s[1 + ss * 6 + 0] += xv * ra[ss * 2048 + v];
            s[1 + ss * 6 + 1] += xv * ra[ss * 2048 + 1024 + v];
#pragma unroll
            for (int hh = 0; hh < 2; hh++) {
                const float* rb = ratt + (((size_t)(ss * 2 + hh) * 8 + b)) * 2048;
                s[1 + ss * 6 + 2 + hh * 2] += xv * rb[v];
                s[1 + ss * 6 + 3 + hh * 2] += xv * rb[1024 + v];
            }
        }
    }
    int wid = t >> 6, lane = t & 63;
#pragma unroll
    for (int i = 0; i < 13; i++)
#pragma unroll
        for (int off = 1; off < 64; off <<= 1) s[i] += __shfl_xor(s[i], off);
    __shared__ float red[13][4];
    if (lane == 0)
#pragma unroll
        for (int i = 0; i < 13; i++) red[i][wid] = s[i];
    __syncthreads();
    if (t < 13) {
        float tot = red[t][0] + red[t][1] + red[t][2] + red[t][3];
        feats[(size_t)b * 832 + t * 64 + d] = tot * (1.f / (1024.f * 12.f));
    }
}

__global__ void k_gate(const float* __restrict__ feats, const float* __restrict__ aw,
                       const float* __restrict__ ab, float* __restrict__ gate) {
    int b = blockIdx.x, t = threadIdx.x;
    __shared__ float lg[13];
    if (t < 13) {
        float s = ab[t];
        const float* f = feats + (size_t)b * 832;
        const float* w = aw + (size_t)t * 832;
        for (int k = 0; k < 832; k++) s += f[k] * w[k];
        lg[t] = s;
    }
    __syncthreads();
    if (t == 0) {
        float m = lg[0];
        for (int j = 1; j < 13; j++) m = fmaxf(m, lg[j]);
        float ss = 0.f;
        for (int j = 0; j < 13; j++) ss += __expf(lg[j] - m);
        float inv = 1.f / ss;
        for (int j = 0; j < 13; j++) gate[b * 13 + j] = __expf(lg[j] - m) * inv;
    }
}

// ---------- z-projection, in place on XT, LDS-staged ----------
__global__ __launch_bounds__(256) void k_zt2(f16* __restrict__ XT,
                                             const float* __restrict__ fw) {
    __shared__ f16 xs[64][136];
    __shared__ float fws[64][64];
    int nt = blockIdx.x, l = blockIdx.y, b = blockIdx.z;
    int t = threadIdx.x;
    f16* base = XT + (size_t)b * 786432 + (size_t)l * 1024 + nt * 128;
#pragma unroll
    for (int it = 0; it < 4; it++) {
        int idx = it * 256 + t;
        int row = idx >> 4, c = idx & 15;
        *reinterpret_cast<f16x8*>(&xs[row][c * 8]) =
            *reinterpret_cast<const f16x8*>(base + (size_t)row * 12288 + c * 8);
    }
    for (int i = t; i < 4096; i += 256) ((float*)fws)[i] = fw[i];
    __syncthreads();
    int nl = t & 31, og = t >> 5;
    float acc[8][4];
#pragma unroll
    for (int oo = 0; oo < 8; oo++)
#pragma unroll
        for (int j = 0; j < 4; j++) acc[oo][j] = 0.f;
#pragma unroll 4
    for (int d = 0; d < 64; d++) {
        f16x4 xv = *reinterpret_cast<const f16x4*>(&xs[d][nl * 4]);
        float x0 = (float)xv[0], x1 = (float)xv[1], x2 = (float)xv[2], x3 = (float)xv[3];
#pragma unroll
        for (int oo = 0; oo < 8; oo++) {
            float w = fws[og * 8 + oo][d];
            acc[oo][0] += w * x0; acc[oo][1] += w * x1;
            acc[oo][2] += w * x2; acc[oo][3] += w * x3;
        }
    }
#pragma unroll
    for (int oo = 0; oo < 8; oo++) {
        int o = og * 8 + oo;
        f16x4 ov;
        ov[0] = (f16)acc[oo][0]; ov[1] = (f16)acc[oo][1];
        ov[2] = (f16)acc[oo][2]; ov[3] = (f16)acc[oo][3];
        *reinterpret_cast<f16x4*>(base + (size_t)o * 12288 + nl * 4) = ov;
    }
}

// ---- final: out = fb + g0*Z + sum_j (g1j*P1[j] + g2j*P2[j]), layout fix ----
__global__ void k_out(const f16* __restrict__ ZT, const f16* __restrict__ P1all,
                      const f16* __restrict__ P2all, const float* __restrict__ gate,
                      const float* __restrict__ fb, float* __restrict__ out) {
    int idx = blockIdx.x * 256 + threadIdx.x;
    int n = idx & 1023, o = (idx >> 10) & 63, b = idx >> 16;
    const float* g = gate + b * 13;
    size_t rowbase = ((size_t)b * 768 + o * 12) * 1024 + n;
    float v[12];
    float g0 = g[0], fbv = fb[o];
#pragma unroll
    for (int l = 0; l < 12; l++)
        v[l] = fbv + g0 * (float)ZT[rowbase + (size_t)l * 1024];
#pragma unroll
    for (int j = 0; j < 6; j++) {
        float g1 = g[1 + 2 * j], g2 = g[2 + 2 * j];
        const f16* p1 = P1all + (size_t)j * 6291456 + rowbase;
        const f16* p2 = P2all + (size_t)j * 6291456 + rowbase;
#pragma unroll
        for (int l = 0; l < 12; l++)
            v[l] += g1 * (float)p1[(size_t)l * 1024] + g2 * (float)p2[(size_t)l * 1024];
    }
    float4* dst = reinterpret_cast<float4*>(out + (((size_t)b * 64 + o) * 1024 + n) * 12);
    float4 o0 = {v[0], v[1], v[2], v[3]};
    float4 o1 = {v[4], v[5], v[6], v[7]};
    float4 o2 = {v[8], v[9], v[10], v[11]};
    dst[0] = o0; dst[1] = o1; dst[2] = o2;
}

// ================= launch ===================================================

extern "C" void kernel_launch(void* const* d_in, const int* in_sizes, int n_in,
                              void* d_out, int out_size, void* d_ws, size_t ws_size,
                              hipStream_t stream) {
    const float* x   = (const float*)d_in[0];
    const float* sup = (const float*)d_in[1];
    const float* nv1 = (const float*)d_in[2];
    const float* nv2 = (const float*)d_in[3];
    const float* kw  = (const float*)d_in[4];
    const float* kb  = (const float*)d_in[5];
    const float* qw  = (const float*)d_in[6];
    const float* qb  = (const float*)d_in[7];
    const float* aw  = (const float*)d_in[8];
    const float* ab  = (const float*)d_in[9];
    const float* fw  = (const float*)d_in[10];
    const float* fb  = (const float*)d_in[11];
    float* hout = (float*)d_out;

    float* wsf = (float*)d_ws;
    size_t o = 0;
    f16*   XT     = (f16*)(wsf + o);  o += 3145728;
    float* attReg = wsf + o;          o += 16777216;
    f16*   attT   = (f16*)attReg;
    f16*   xT2    = (f16*)attReg;
    f16*   aT     = (f16*)(wsf + o);  o += 1048576;
    float* gate   = wsf + o;          o += 128;
    size_t rc = o;
    // ---- phase A ----
    size_t oA = rc;
    f16*   scTall = (f16*)(wsf + oA);  oA += 8388608;
    f16*   keysT  = (f16*)(wsf + oA);  oA += 2097152;
    f16*   kwb    = (f16*)(wsf + oA);  oA += 196608;
    float* kwl    = wsf + oA;          oA += 32768;
    float* tkq    = wsf + oA;          oA += 524288;
    float* xl     = wsf + oA;          oA += 524288;
    float* ra     = wsf + oA;          oA += 4096;
    float* ratt   = wsf + oA;          oA += 65536;
    float* feats  = wsf + oA;          oA += 6656;
    float* partial= wsf + oA;          oA += 1114112;
    // ---- phase B ----
    size_t oB = rc;
    f16*   P1all  = (f16*)(wsf + oB); oB += 18874368;
    f16*   P2all  = (f16*)(wsf + oB); oB += 18874368;
    size_t need = ((oA > oB) ? oA : oB) * 4;
    if (ws_size < need) return;

    f16* ZT = XT;

    k_xtfused<<<dim3(16, 4, 8), 256, 0, stream>>>(x, XT, xT2, xl);
    k_wcvt<<<128, 256, 0, stream>>>(kw, qw, kwl, kwb);
    k_tkq<<<2048, 256, 0, stream>>>(kwl, nv1, nv2, kb, qb, tkq);
    k_acvt<<<dim3(16, 16, 2), 256, 0, stream>>>(sup, aT);

    k_kqgemm<<<dim3(8, 1, 32), 256, 0, stream>>>(xT2, kwb, tkq, keysT);

    k_scoregemm2<<<dim3(8, 8, 16), 256, 0, stream>>>(keysT, scTall);
    k_softmax3<<<4096, 256, 0, stream>>>(scTall, aT, attT);

    k_colsum1<0><<<dim3(16, 34), 256, 0, stream>>>(aT, attT, ra, ratt, partial);
    k_colsum2<0><<<34, 256, 0, stream>>>(partial, ra, ratt);
    k_colsum1<1><<<dim3(16, 34), 256, 0, stream>>>(aT, attT, ra, ratt, partial);
    k_colsum2<1><<<34, 256, 0, stream>>>(partial, ra, ratt);
    k_feat13<<<512, 256, 0, stream>>>(xl, ra, ratt, feats);
    k_gate<<<8, 64, 0, stream>>>(feats, aw, ab, gate);

    k_zt2<<<dim3(8, 12, 8), 256, 0, stream>>>(XT, fw);

    k_prop1m<<<2304, 256, 0, stream>>>(ZT, aT, attT, P1all);
    k_prop2m<<<2304, 256, 0, stream>>>(P1all, aT, attT, P2all);
    k_out<<<2048, 256, 0, stream>>>(ZT, P1all, P2all, gate, fb, hout);
}